// Round 1
// baseline (2083.618 us; speedup 1.0000x reference)
//
#include <hip/hip_runtime.h>

#define N_ 4
#define C_ 64
#define H_ 224
#define W_ 224
#define HW_ (H_ * W_)        /* 50176 */
#define CHW_ (C_ * HW_)      /* 3211264 */
#define TOT_ (N_ * CHW_)     /* 12845056 */

// t[idx] = shared_conv(x)[idx] + x[idx]   (depthwise 3x3, same 9 weights per channel)
__global__ __launch_bounds__(256) void dw_res_kernel(
    const float* __restrict__ x, const float* __restrict__ wsh,
    float* __restrict__ t)
{
    float wk[9];
#pragma unroll
    for (int k = 0; k < 9; ++k) wk[k] = wsh[k];

    for (int idx = blockIdx.x * 256 + threadIdx.x; idx < TOT_;
         idx += gridDim.x * 256) {
        int w = idx % W_;
        int h = (idx / W_) % H_;
        const float* b = x + idx;
        float center = b[0];
        bool hm = h > 0, hp = h < H_ - 1, wm = w > 0, wp = w < W_ - 1;
        float s = wk[4] * center;
        s += (hm && wm) ? wk[0] * b[-W_ - 1] : 0.f;
        s += hm         ? wk[1] * b[-W_]     : 0.f;
        s += (hm && wp) ? wk[2] * b[-W_ + 1] : 0.f;
        s += wm         ? wk[3] * b[-1]      : 0.f;
        s += wp         ? wk[5] * b[1]       : 0.f;
        s += (hp && wm) ? wk[6] * b[W_ - 1]  : 0.f;
        s += hp         ? wk[7] * b[W_]      : 0.f;
        s += (hp && wp) ? wk[8] * b[W_ + 1]  : 0.f;
        t[idx] = s + center;
    }
}

// out[n,o,h,w] = sum_i sum_k wd[o,i,k] * t[n,i,h+dy,w+dx] + bd[o] + res[n,o,h,w]
// res may alias out (in-place residual): each element is read by exactly the
// thread that later writes it, so res/out are NOT __restrict__.
__global__ __launch_bounds__(256) void conv_dense_kernel(
    const float* __restrict__ t, const float* __restrict__ wd,
    const float* __restrict__ bd, const float* res, float* out)
{
    const int tx = threadIdx.x & 31;
    const int ty = threadIdx.x >> 5;
    const int w = blockIdx.x * 32 + tx;
    const int h = blockIdx.y * 8 + ty;
    const int n = blockIdx.z;
    const int nbase = n * CHW_;
    const int pix = h * W_ + w;

    float acc[64];
#pragma unroll
    for (int o = 0; o < 64; ++o)
        acc[o] = bd[o] + res[nbase + o * HW_ + pix];

    const bool hm = h > 0, hp = h < H_ - 1, wm = w > 0, wp = w < W_ - 1;

    for (int i = 0; i < C_; ++i) {
        const float* b = t + nbase + i * HW_ + pix;
        float v[9];
        v[0] = (hm && wm) ? b[-W_ - 1] : 0.f;
        v[1] = hm         ? b[-W_]     : 0.f;
        v[2] = (hm && wp) ? b[-W_ + 1] : 0.f;
        v[3] = wm         ? b[-1]      : 0.f;
        v[4] = b[0];
        v[5] = wp         ? b[1]       : 0.f;
        v[6] = (hp && wm) ? b[W_ - 1]  : 0.f;
        v[7] = hp         ? b[W_]      : 0.f;
        v[8] = (hp && wp) ? b[W_ + 1]  : 0.f;

        const float* wrow = wd + i * 9;
#pragma unroll
        for (int o = 0; o < 64; ++o) {
            const float* wo = wrow + o * 576;  // wd[o][i][0..8] contiguous
#pragma unroll
            for (int k = 0; k < 9; ++k)
                acc[o] = fmaf(wo[k], v[k], acc[o]);
        }
    }

#pragma unroll
    for (int o = 0; o < 64; ++o)
        out[nbase + o * HW_ + pix] = acc[o];
}

// Per-channel batch stats over (N,H,W): stats[c]=mean, stats[64+c]=rsqrt(var+eps)
__global__ __launch_bounds__(256) void bn_stats_kernel(
    const float* __restrict__ p, float* __restrict__ stats)
{
    const int c = blockIdx.x;
    float s = 0.f, s2 = 0.f;
    for (int n = 0; n < N_; ++n) {
        const float* base = p + n * CHW_ + c * HW_;
        for (int i = threadIdx.x; i < HW_; i += 256) {
            float v = base[i];
            s += v;
            s2 = fmaf(v, v, s2);
        }
    }
    __shared__ float rs[256], rs2[256];
    rs[threadIdx.x] = s;
    rs2[threadIdx.x] = s2;
    __syncthreads();
    for (int off = 128; off > 0; off >>= 1) {
        if (threadIdx.x < off) {
            rs[threadIdx.x] += rs[threadIdx.x + off];
            rs2[threadIdx.x] += rs2[threadIdx.x + off];
        }
        __syncthreads();
    }
    if (threadIdx.x == 0) {
        const float cnt = (float)(N_ * HW_);
        float mean = rs[0] / cnt;
        float var = rs2[0] / cnt - mean * mean;
        stats[c] = mean;
        stats[64 + c] = rsqrtf(var + 1e-5f);
    }
}

// out = relu(gamma*(p-mean)*inv + beta) (+ addx if non-null). p may alias out.
__global__ __launch_bounds__(256) void bn_norm_kernel(
    const float* p, const float* __restrict__ stats,
    const float* __restrict__ gamma, const float* __restrict__ beta,
    const float* __restrict__ addx, float* out)
{
    for (int idx = blockIdx.x * 256 + threadIdx.x; idx < TOT_;
         idx += gridDim.x * 256) {
        int c = (idx / HW_) & (C_ - 1);
        float m = stats[c], inv = stats[64 + c];
        float v = fmaf((p[idx] - m) * inv, gamma[c], beta[c]);
        v = fmaxf(v, 0.f);
        if (addx) v += addx[idx];
        out[idx] = v;
    }
}

extern "C" void kernel_launch(void* const* d_in, const int* in_sizes, int n_in,
                              void* d_out, int out_size, void* d_ws, size_t ws_size,
                              hipStream_t stream)
{
    const float* x    = (const float*)d_in[0];
    const float* wsh1 = (const float*)d_in[1];
    const float* wd1  = (const float*)d_in[2];
    const float* bd1  = (const float*)d_in[3];
    const float* wsh2 = (const float*)d_in[4];
    const float* wd2  = (const float*)d_in[5];
    const float* bd2  = (const float*)d_in[6];
    const float* g1   = (const float*)d_in[7];
    const float* be1  = (const float*)d_in[8];
    const float* g2   = (const float*)d_in[9];
    const float* be2  = (const float*)d_in[10];

    float* out   = (float*)d_out;
    float* t     = (float*)d_ws;          // TOT_ floats
    float* stats = t + TOT_;              // 256 floats

    dim3 cgrid(W_ / 32, H_ / 8, N_);      // (7, 28, 4) = 784 blocks
    const int sgrid = 2048;

    // ---- layer 1 ----
    dw_res_kernel<<<sgrid, 256, 0, stream>>>(x, wsh1, t);
    conv_dense_kernel<<<cgrid, 256, 0, stream>>>(t, wd1, bd1, x, out);
    bn_stats_kernel<<<64, 256, 0, stream>>>(out, stats);
    bn_norm_kernel<<<sgrid, 256, 0, stream>>>(out, stats, g1, be1, nullptr, out);

    // ---- layer 2 (residual base = o1, held in d_out; in-place) ----
    dw_res_kernel<<<sgrid, 256, 0, stream>>>(out, wsh2, t);
    conv_dense_kernel<<<cgrid, 256, 0, stream>>>(t, wd2, bd2, out, out);
    bn_stats_kernel<<<64, 256, 0, stream>>>(out, stats + 128);
    bn_norm_kernel<<<sgrid, 256, 0, stream>>>(out, stats + 128, g2, be2, x, out);
}

// Round 2
// 1965.903 us; speedup vs baseline: 1.0599x; 1.0599x over previous
//
#include <hip/hip_runtime.h>

#define N_ 4
#define C_ 64
#define H_ 224
#define W_ 224
#define HW_ (H_ * W_)        /* 50176 */
#define CHW_ (C_ * HW_)      /* 3211264 */
#define TOT_ (N_ * CHW_)     /* 12845056 */

#define TW 32
#define TH 8

__device__ __forceinline__ float relu_(float v) { return fmaxf(v, 0.f); }

// Fused kernel: per 32x8 output tile, loop over input channels in chunks of 8.
//   stage: x (or normalized o1) halo tile -> LDS, weights chunk -> LDS
//   t = shared_conv(in)+in computed in LDS (zeroed outside image = conv padding)
//   dense 3x3 conv accumulated in registers (64 outputs/thread: 16 o x 4 w)
//   epilogue: + bias + residual(src, normalized if NORM), write dst,
//             per-channel sum/sumsq wave-reduced and atomically accumulated.
template<bool NORM>
__global__ __launch_bounds__(256, 3) void conv_fused(
    const float* __restrict__ src,   // x (layer1) or o1 raw (layer2)
    const float* __restrict__ wsh,   // 9 shared-conv weights
    const float* __restrict__ wd,    // [64][64][9]
    const float* __restrict__ bd,    // [64]
    const float* __restrict__ ss,    // [scale64][shift64] for input norm (NORM only)
    float* __restrict__ dst,
    float* __restrict__ raw)         // [sum64][sumsq64] atomic accumulator
{
    __shared__ float Xs[8][12][37];  // input halo tile (12x36 used, +1 pad)
    __shared__ float Ts[8][350];     // t tile, [rr*35+cc], 10x34 used
    __shared__ float Ws[8][9][68];   // weights [ich][k][o], padded 64->68
    __shared__ float SS[128];

    const int tid = threadIdx.x;
    const int n  = blockIdx.z;
    const int h0 = blockIdx.y * TH;
    const int w0 = blockIdx.x * TW;

    float wk[9];
#pragma unroll
    for (int k = 0; k < 9; ++k) wk[k] = wsh[k];
    const float wk4p1 = wk[4] + 1.f;   // fold "+ center" of t = dw(x)+x

    if (NORM) { if (tid < 128) SS[tid] = ss[tid]; }

    const int wg = tid >> 6;           // o-group (wave): o = wg*16 .. wg*16+15
    const int lane = tid & 63;
    const int q = lane & 7;            // w-quad: w = w0 + 4q .. 4q+3
    const int r = lane >> 3;           // row:    h = h0 + r

    float acc[16][4];
#pragma unroll
    for (int og = 0; og < 16; ++og)
#pragma unroll
        for (int p = 0; p < 4; ++p) acc[og][p] = 0.f;

    const float* srcn = src + n * CHW_;

    for (int c8 = 0; c8 < 8; ++c8) {
        const int ic0 = c8 * 8;
        __syncthreads();  // protect LDS reuse (and SS on first iter)

        // ---- stage input halo tile (zero outside image, norm if layer2) ----
        for (int f = tid; f < 8 * 12 * 36; f += 256) {
            int ch  = f / 432;
            int rem = f - ch * 432;
            int rr  = rem / 36;
            int cc  = rem - rr * 36;
            int gh = h0 - 2 + rr, gw = w0 - 2 + cc;
            float v = 0.f;
            if ((unsigned)gh < (unsigned)H_ && (unsigned)gw < (unsigned)W_) {
                v = srcn[(ic0 + ch) * HW_ + gh * W_ + gw];
                if (NORM) v = relu_(fmaf(SS[ic0 + ch], v, SS[64 + ic0 + ch]));
            }
            Xs[ch][rr][cc] = v;
        }
        // ---- stage weights chunk: global [o][ic0+ich][k] -> LDS [ich][k][o] ----
        for (int f = tid; f < 8 * 576; f += 256) {   // 18 exact iters
            int o = f / 72;
            int j = f - o * 72;                       // j = ich*9 + k (contiguous in global)
            int ch = j / 9;
            int k  = j - ch * 9;
            Ws[ch][k][o] = wd[o * 576 + ic0 * 9 + j];
        }
        __syncthreads();

        // ---- t = shared_conv(in) + in, zero outside image ----
        for (int f = tid; f < 8 * 340; f += 256) {
            int ch  = f / 340;
            int rem = f - ch * 340;
            int rr  = rem / 34;
            int cc  = rem - rr * 34;
            int gh = h0 - 1 + rr, gw = w0 - 1 + cc;
            float tv = 0.f;
            if ((unsigned)gh < (unsigned)H_ && (unsigned)gw < (unsigned)W_) {
                tv = wk4p1 * Xs[ch][rr + 1][cc + 1];
                tv = fmaf(wk[0], Xs[ch][rr    ][cc    ], tv);
                tv = fmaf(wk[1], Xs[ch][rr    ][cc + 1], tv);
                tv = fmaf(wk[2], Xs[ch][rr    ][cc + 2], tv);
                tv = fmaf(wk[3], Xs[ch][rr + 1][cc    ], tv);
                tv = fmaf(wk[5], Xs[ch][rr + 1][cc + 2], tv);
                tv = fmaf(wk[6], Xs[ch][rr + 2][cc    ], tv);
                tv = fmaf(wk[7], Xs[ch][rr + 2][cc + 1], tv);
                tv = fmaf(wk[8], Xs[ch][rr + 2][cc + 2], tv);
            }
            Ts[ch][rr * 35 + cc] = tv;
        }
        __syncthreads();

        // ---- dense conv accumulate ----
#pragma unroll
        for (int ich = 0; ich < 8; ++ich) {
            float nb[3][6];
#pragma unroll
            for (int dr = 0; dr < 3; ++dr)
#pragma unroll
                for (int j = 0; j < 6; ++j)
                    nb[dr][j] = Ts[ich][(r + dr) * 35 + 4 * q + j];
#pragma unroll
            for (int k = 0; k < 9; ++k) {
                const int dr = k / 3, dc = k - dr * 3;
                float4 wa = *(const float4*)&Ws[ich][k][wg * 16];
                float4 wb = *(const float4*)&Ws[ich][k][wg * 16 + 4];
                float4 wc = *(const float4*)&Ws[ich][k][wg * 16 + 8];
                float4 wdq = *(const float4*)&Ws[ich][k][wg * 16 + 12];
                float wv[16] = { wa.x, wa.y, wa.z, wa.w, wb.x, wb.y, wb.z, wb.w,
                                 wc.x, wc.y, wc.z, wc.w, wdq.x, wdq.y, wdq.z, wdq.w };
#pragma unroll
                for (int og = 0; og < 16; ++og)
#pragma unroll
                    for (int p = 0; p < 4; ++p)
                        acc[og][p] = fmaf(wv[og], nb[dr][p + dc], acc[og][p]);
            }
        }
    }

    // ---- epilogue: bias + residual + store + stats ----
    const int h = h0 + r, w = w0 + 4 * q;
    const int pb = n * CHW_ + h * W_ + w;
#pragma unroll
    for (int og = 0; og < 16; ++og) {
        const int o = wg * 16 + og;
        float4 rv = *(const float4*)(src + pb + o * HW_);
        if (NORM) {
            float sc = SS[o], sh = SS[64 + o];
            rv.x = relu_(fmaf(sc, rv.x, sh));
            rv.y = relu_(fmaf(sc, rv.y, sh));
            rv.z = relu_(fmaf(sc, rv.z, sh));
            rv.w = relu_(fmaf(sc, rv.w, sh));
        }
        const float b = bd[o];
        float4 vo;
        vo.x = acc[og][0] + b + rv.x;
        vo.y = acc[og][1] + b + rv.y;
        vo.z = acc[og][2] + b + rv.z;
        vo.w = acc[og][3] + b + rv.w;
        *(float4*)(dst + pb + o * HW_) = vo;

        float s1 = (vo.x + vo.y) + (vo.z + vo.w);
        float s2 = fmaf(vo.x, vo.x, fmaf(vo.y, vo.y, fmaf(vo.z, vo.z, vo.w * vo.w)));
#pragma unroll
        for (int off = 32; off > 0; off >>= 1) {
            s1 += __shfl_xor(s1, off);
            s2 += __shfl_xor(s2, off);
        }
        if (lane == 0) {
            atomicAdd(&raw[o], s1);
            atomicAdd(&raw[64 + o], s2);
        }
    }
}

// raw sums -> scale/shift:  n = relu(scale*v + shift)
__global__ void stats_fin(const float* __restrict__ raw, const float* __restrict__ gamma,
                          const float* __restrict__ beta, float* __restrict__ ss)
{
    int c = threadIdx.x;
    if (c < 64) {
        const float cnt = (float)(N_ * HW_);
        float mean = raw[c] / cnt;
        float var  = raw[64 + c] / cnt - mean * mean;
        float inv  = rsqrtf(var + 1e-5f);
        float sc   = gamma[c] * inv;
        ss[c]      = sc;
        ss[64 + c] = fmaf(-sc, mean, beta[c]);
    }
}

// out = relu(bn2(o2)) + x
__global__ __launch_bounds__(256) void final_k(
    const float4* __restrict__ o2, const float* __restrict__ ss,
    const float4* __restrict__ x, float4* __restrict__ out)
{
    const int nq = TOT_ / 4;
    for (int i = blockIdx.x * 256 + threadIdx.x; i < nq; i += gridDim.x * 256) {
        int c = (i / (HW_ / 4)) & 63;
        float sc = ss[c], sh = ss[64 + c];
        float4 v = o2[i], xx = x[i];
        float4 rr;
        rr.x = relu_(fmaf(sc, v.x, sh)) + xx.x;
        rr.y = relu_(fmaf(sc, v.y, sh)) + xx.y;
        rr.z = relu_(fmaf(sc, v.z, sh)) + xx.z;
        rr.w = relu_(fmaf(sc, v.w, sh)) + xx.w;
        out[i] = rr;
    }
}

extern "C" void kernel_launch(void* const* d_in, const int* in_sizes, int n_in,
                              void* d_out, int out_size, void* d_ws, size_t ws_size,
                              hipStream_t stream)
{
    const float* x    = (const float*)d_in[0];
    const float* wsh1 = (const float*)d_in[1];
    const float* wd1  = (const float*)d_in[2];
    const float* bd1  = (const float*)d_in[3];
    const float* wsh2 = (const float*)d_in[4];
    const float* wd2  = (const float*)d_in[5];
    const float* bd2  = (const float*)d_in[6];
    const float* g1   = (const float*)d_in[7];
    const float* be1  = (const float*)d_in[8];
    const float* g2   = (const float*)d_in[9];
    const float* be2  = (const float*)d_in[10];

    float* out  = (float*)d_out;
    float* A    = (float*)d_ws;        // o2 buffer, TOT_ floats
    float* raw1 = A + TOT_;            // 128
    float* raw2 = raw1 + 128;          // 128
    float* ss1  = raw2 + 128;          // 128
    float* ss2  = ss1 + 128;           // 128

    hipMemsetAsync(raw1, 0, 256 * sizeof(float), stream);  // zero both raw accums

    dim3 grid(W_ / TW, H_ / TH, N_);   // (7, 28, 4)

    // layer 1: o1 = conv(dw(x)+x) + b + x  -> d_out; stats1
    conv_fused<false><<<grid, 256, 0, stream>>>(x, wsh1, wd1, bd1, nullptr, out, raw1);
    stats_fin<<<1, 64, 0, stream>>>(raw1, g1, be1, ss1);
    // layer 2: n1 = relu(bn1(o1)) on the fly; o2 = conv(dw(n1)+n1) + b + n1 -> ws; stats2
    conv_fused<true><<<grid, 256, 0, stream>>>(out, wsh2, wd2, bd2, ss1, A, raw2);
    stats_fin<<<1, 64, 0, stream>>>(raw2, g2, be2, ss2);
    // out = relu(bn2(o2)) + x
    final_k<<<1024, 256, 0, stream>>>((const float4*)A, ss2, (const float4*)x, (float4*)out);
}

// Round 3
// 445.161 us; speedup vs baseline: 4.6806x; 4.4162x over previous
//
#include <hip/hip_runtime.h>

#define N_ 4
#define C_ 64
#define H_ 224
#define W_ 224
#define HW_ (H_ * W_)        /* 50176 */
#define CHW_ (C_ * HW_)      /* 3211264 */
#define TOT_ (N_ * CHW_)     /* 12845056 */

typedef __bf16 bf8 __attribute__((ext_vector_type(8)));
typedef float  f4  __attribute__((ext_vector_type(4)));

__device__ __forceinline__ float relu_(float v) { return fmaxf(v, 0.f); }

__device__ __forceinline__ unsigned short f2bf(float f) {
    unsigned u = __builtin_bit_cast(unsigned, f);
    return (unsigned short)((u + 0x7FFFu + ((u >> 16) & 1u)) >> 16);
}

// Pre-convert both dense-conv weights to bf16 in the exact (chunk-major,
// XOR-swizzled) image the conv kernel's LDS wants:
//   Wpre[sel][cc][tap][o][e]  (uint16), e = (k&7) | ((((k>>3)^(o>>1))&3)<<3)
__global__ __launch_bounds__(256) void prep_w(
    const float* __restrict__ wd1, const float* __restrict__ wd2,
    unsigned short* __restrict__ wpre)
{
    int i = blockIdx.x * 256 + threadIdx.x;
    if (i >= 73728) return;
    int sel = i / 36864;
    int r   = i - sel * 36864;
    int cc  = r / 18432;
    int r2  = r - cc * 18432;
    int tap = r2 / 2048;
    int r3  = r2 - tap * 2048;
    int o   = r3 >> 5, k = r3 & 31;
    const float* wsrc = sel ? wd2 : wd1;
    float v = wsrc[o * 576 + (cc * 32 + k) * 9 + tap];
    int e = (k & 7) | ((((k >> 3) ^ (o >> 1)) & 3) << 3);
    wpre[sel * 36864 + cc * 18432 + tap * 2048 + o * 32 + e] = f2bf(v);
}

// Fused SDC layer via MFMA implicit GEMM.
// Per 32x8 output tile: for each ich-chunk of 32:
//   T = shared_conv(in)+in (normalized in if NORM) computed from GLOBAL into
//   LDS bf16 [340 halo pix][32 ich], XOR-swizzled; W chunk copied (pre-swizzled).
//   9 taps x 1 K-step of mfma_f32_16x16x32_bf16 into f32 acc[4][4] per wave.
// Epilogue: + bias + residual(src, normalized if NORM) -> dst; per-channel
// sum/sumsq block-reduced, one atomicAdd per channel per block.
template<bool NORM>
__global__ __launch_bounds__(256, 2) void conv_mfma(
    const float* __restrict__ src,            // x (L1) or raw o1 (L2)
    const float* __restrict__ wsh,            // 9 shared-conv weights
    const unsigned short* __restrict__ wpre,  // this layer's pre-swizzled W
    const float* __restrict__ bd,
    const float* __restrict__ ss,             // [scale64][shift64] (NORM)
    float* __restrict__ dst,
    float* __restrict__ raw)                  // [sum64][sumsq64]
{
    __shared__ __align__(16) char TlB[340 * 64];    // 21760 B
    __shared__ __align__(16) char WlB[9 * 64 * 64]; // 36864 B
    __shared__ float SS[128];
    __shared__ float Sred[4][128];

    const int tid = threadIdx.x;
    const int n  = blockIdx.z;
    const int h0 = blockIdx.y * 8;
    const int w0 = blockIdx.x * 32;
    const int lane = tid & 63, wg = tid >> 6;
    const int l15 = lane & 15, lg = lane >> 4;

    float wk[9];
#pragma unroll
    for (int k = 0; k < 9; ++k) wk[k] = wsh[k];
    const float wk4p1 = wk[4] + 1.f;

    if (NORM && tid < 128) SS[tid] = ss[tid];
    __syncthreads();

    const float* srcn = src + n * CHW_;

    f4 acc[4][4];
#pragma unroll
    for (int mf = 0; mf < 4; ++mf)
#pragma unroll
        for (int nf = 0; nf < 4; ++nf) acc[mf][nf] = (f4){0.f, 0.f, 0.f, 0.f};

    for (int cc = 0; cc < 2; ++cc) {
        if (cc) __syncthreads();
        const int ic0 = cc * 32;

        // ---- stage W chunk (linear copy of pre-swizzled image) ----
        {
            const float4* ws4 = (const float4*)(wpre + cc * 18432);
            float4* wl4 = (float4*)WlB;
#pragma unroll
            for (int j = 0; j < 9; ++j) wl4[tid + 256 * j] = ws4[tid + 256 * j];
        }

        // ---- produce T halo tile (340 pix x 32 ich) from global ----
        for (int it = tid; it < 5440; it += 256) {
            int ich2 = it / 340;             // channel pair 0..15
            int p    = it - ich2 * 340;      // halo pixel
            int hh = p / 34;
            int ww = p - hh * 34;
            int gh = h0 - 1 + hh, gw = w0 - 1 + ww;
            unsigned pk = 0u;
            if ((unsigned)gh < (unsigned)H_ && (unsigned)gw < (unsigned)W_) {
                const bool ym = gh > 0, yp = gh < H_ - 1;
                const bool xm = gw > 0, xp = gw < W_ - 1;
                float tv0, tv1;
#pragma unroll
                for (int sub = 0; sub < 2; ++sub) {
                    const int c = ic0 + ich2 * 2 + sub;
                    const float* base = srcn + c * HW_ + gh * W_ + gw;
                    float sc = 1.f, sh = 0.f;
                    if (NORM) { sc = SS[c]; sh = SS[64 + c]; }
                    float v4 = base[0];
                    if (NORM) v4 = relu_(fmaf(sc, v4, sh));
                    float v0 = 0.f, v1 = 0.f, v2 = 0.f, v3 = 0.f;
                    float v5 = 0.f, v6 = 0.f, v7 = 0.f, v8 = 0.f;
                    if (ym && xm) { v0 = base[-W_ - 1]; if (NORM) v0 = relu_(fmaf(sc, v0, sh)); }
                    if (ym)       { v1 = base[-W_];     if (NORM) v1 = relu_(fmaf(sc, v1, sh)); }
                    if (ym && xp) { v2 = base[-W_ + 1]; if (NORM) v2 = relu_(fmaf(sc, v2, sh)); }
                    if (xm)       { v3 = base[-1];      if (NORM) v3 = relu_(fmaf(sc, v3, sh)); }
                    if (xp)       { v5 = base[1];       if (NORM) v5 = relu_(fmaf(sc, v5, sh)); }
                    if (yp && xm) { v6 = base[W_ - 1];  if (NORM) v6 = relu_(fmaf(sc, v6, sh)); }
                    if (yp)       { v7 = base[W_];      if (NORM) v7 = relu_(fmaf(sc, v7, sh)); }
                    if (yp && xp) { v8 = base[W_ + 1];  if (NORM) v8 = relu_(fmaf(sc, v8, sh)); }
                    float t = wk4p1 * v4;
                    t = fmaf(wk[0], v0, t); t = fmaf(wk[1], v1, t);
                    t = fmaf(wk[2], v2, t); t = fmaf(wk[3], v3, t);
                    t = fmaf(wk[5], v5, t); t = fmaf(wk[6], v6, t);
                    t = fmaf(wk[7], v7, t); t = fmaf(wk[8], v8, t);
                    if (sub == 0) tv0 = t; else tv1 = t;
                }
                pk = (unsigned)f2bf(tv0) | ((unsigned)f2bf(tv1) << 16);
            }
            int byte = p * 64 + ((ich2 & 3) << 2) +
                       ((((ich2 >> 2) ^ (p >> 1)) & 3) << 4);
            *(unsigned*)(TlB + byte) = pk;
        }
        __syncthreads();

        // ---- MFMA: 9 taps x (4 B-frags, 4 A-frags, 16 MFMA) ----
#pragma unroll
        for (int tap = 0; tap < 9; ++tap) {
            const int dr = tap / 3, dc = tap - dr * 3;
            bf8 B[4];
#pragma unroll
            for (int nf = 0; nf < 4; ++nf) {
                const int o = nf * 16 + l15;
                B[nf] = *(const bf8*)(WlB + tap * 4096 + o * 64 +
                                      (((lg ^ (o >> 1)) & 3) << 4));
            }
#pragma unroll
            for (int mf = 0; mf < 4; ++mf) {
                const int row = (wg * 2 + (mf >> 1) + dr) * 34 + (mf & 1) * 16 + dc + l15;
                const bf8 A = *(const bf8*)(TlB + row * 64 +
                                            (((lg ^ (row >> 1)) & 3) << 4));
#pragma unroll
                for (int nf = 0; nf < 4; ++nf)
                    acc[mf][nf] = __builtin_amdgcn_mfma_f32_16x16x32_bf16(
                        A, B[nf], acc[mf][nf], 0, 0, 0);
            }
        }
    }

    // ---- epilogue: bias + residual + store + stats ----
#pragma unroll
    for (int nf = 0; nf < 4; ++nf) {
        const int o = nf * 16 + l15;
        const float bv = bd[o];
        float scO = 1.f, shO = 0.f;
        if (NORM) { scO = SS[o]; shO = SS[64 + o]; }
        float ps1 = 0.f, ps2 = 0.f;
#pragma unroll
        for (int mf = 0; mf < 4; ++mf) {
            const int h = h0 + wg * 2 + (mf >> 1);
            const int w = w0 + (mf & 1) * 16 + lg * 4;
            const int idx = n * CHW_ + o * HW_ + h * W_ + w;
            float4 rv = *(const float4*)(src + idx);
            if (NORM) {
                rv.x = relu_(fmaf(scO, rv.x, shO));
                rv.y = relu_(fmaf(scO, rv.y, shO));
                rv.z = relu_(fmaf(scO, rv.z, shO));
                rv.w = relu_(fmaf(scO, rv.w, shO));
            }
            f4 a = acc[mf][nf];
            float4 vo;
            vo.x = a[0] + bv + rv.x;
            vo.y = a[1] + bv + rv.y;
            vo.z = a[2] + bv + rv.z;
            vo.w = a[3] + bv + rv.w;
            *(float4*)(dst + idx) = vo;
            ps1 += (vo.x + vo.y) + (vo.z + vo.w);
            ps2 += fmaf(vo.x, vo.x, fmaf(vo.y, vo.y, fmaf(vo.z, vo.z, vo.w * vo.w)));
        }
        ps1 += __shfl_xor(ps1, 16); ps1 += __shfl_xor(ps1, 32);
        ps2 += __shfl_xor(ps2, 16); ps2 += __shfl_xor(ps2, 32);
        if (lane < 16) {
            Sred[wg][nf * 16 + lane]      = ps1;
            Sred[wg][64 + nf * 16 + lane] = ps2;
        }
    }
    __syncthreads();
    if (tid < 128) {
        float t = Sred[0][tid] + Sred[1][tid] + Sred[2][tid] + Sred[3][tid];
        atomicAdd(&raw[tid], t);
    }
}

// raw sums -> scale/shift:  n = relu(scale*v + shift)
__global__ void stats_fin(const float* __restrict__ raw, const float* __restrict__ gamma,
                          const float* __restrict__ beta, float* __restrict__ ss)
{
    int c = threadIdx.x;
    if (c < 64) {
        const float cnt = (float)(N_ * HW_);
        float mean = raw[c] / cnt;
        float var  = raw[64 + c] / cnt - mean * mean;
        float inv  = rsqrtf(var + 1e-5f);
        float sc   = gamma[c] * inv;
        ss[c]      = sc;
        ss[64 + c] = fmaf(-sc, mean, beta[c]);
    }
}

// out = relu(bn2(o2)) + x
__global__ __launch_bounds__(256) void final_k(
    const float4* __restrict__ o2, const float* __restrict__ ss,
    const float4* __restrict__ x, float4* __restrict__ out)
{
    const int nq = TOT_ / 4;
    for (int i = blockIdx.x * 256 + threadIdx.x; i < nq; i += gridDim.x * 256) {
        int c = (i / (HW_ / 4)) & 63;
        float sc = ss[c], sh = ss[64 + c];
        float4 v = o2[i], xx = x[i];
        float4 rr;
        rr.x = relu_(fmaf(sc, v.x, sh)) + xx.x;
        rr.y = relu_(fmaf(sc, v.y, sh)) + xx.y;
        rr.z = relu_(fmaf(sc, v.z, sh)) + xx.z;
        rr.w = relu_(fmaf(sc, v.w, sh)) + xx.w;
        out[i] = rr;
    }
}

extern "C" void kernel_launch(void* const* d_in, const int* in_sizes, int n_in,
                              void* d_out, int out_size, void* d_ws, size_t ws_size,
                              hipStream_t stream)
{
    const float* x    = (const float*)d_in[0];
    const float* wsh1 = (const float*)d_in[1];
    const float* wd1  = (const float*)d_in[2];
    const float* bd1  = (const float*)d_in[3];
    const float* wsh2 = (const float*)d_in[4];
    const float* wd2  = (const float*)d_in[5];
    const float* bd2  = (const float*)d_in[6];
    const float* g1   = (const float*)d_in[7];
    const float* be1  = (const float*)d_in[8];
    const float* g2   = (const float*)d_in[9];
    const float* be2  = (const float*)d_in[10];

    float* out  = (float*)d_out;
    float* A    = (float*)d_ws;                 // o2 buffer, TOT_ floats
    float* raw1 = A + TOT_;                     // 128
    float* raw2 = raw1 + 128;                   // 128
    float* ss1  = raw2 + 128;                   // 128
    float* ss2  = ss1 + 128;                    // 128
    unsigned short* Wpre = (unsigned short*)(ss2 + 128);  // 73728 u16

    hipMemsetAsync(raw1, 0, 256 * sizeof(float), stream);

    prep_w<<<288, 256, 0, stream>>>(wd1, wd2, Wpre);

    dim3 grid(W_ / 32, H_ / 8, N_);             // (7, 28, 4)

    // layer 1: o1 = conv(dw(x)+x) + b + x -> d_out; stats1
    conv_mfma<false><<<grid, 256, 0, stream>>>(x, wsh1, Wpre, bd1, nullptr, out, raw1);
    stats_fin<<<1, 64, 0, stream>>>(raw1, g1, be1, ss1);
    // layer 2: n1 = relu(bn1(o1)) on the fly; o2 -> ws A; stats2
    conv_mfma<true><<<grid, 256, 0, stream>>>(out, wsh2, Wpre + 36864, bd2, ss1, A, raw2);
    stats_fin<<<1, 64, 0, stream>>>(raw2, g2, be2, ss2);
    // out = relu(bn2(o2)) + x
    final_k<<<1024, 256, 0, stream>>>((const float4*)A, ss2, (const float4*)x, (float4*)out);
}

// Round 4
// 263.065 us; speedup vs baseline: 7.9205x; 1.6922x over previous
//
#include <hip/hip_runtime.h>

#define N_ 4
#define C_ 64
#define H_ 224
#define W_ 224
#define HW_ (H_ * W_)        /* 50176 */
#define CHW_ (C_ * HW_)      /* 3211264 */
#define TOT_ (N_ * CHW_)     /* 12845056 */

typedef __bf16 bf8 __attribute__((ext_vector_type(8)));
typedef float  f4v __attribute__((ext_vector_type(4)));
typedef unsigned short u16;

__device__ __forceinline__ float relu_(float v) { return fmaxf(v, 0.f); }
__device__ __forceinline__ u16 f2bf(float f) {
    unsigned u = __builtin_bit_cast(unsigned, f);
    return (u16)((u + 0x7FFFu + ((u >> 16) & 1u)) >> 16);
}
__device__ __forceinline__ float bf2f(u16 h) {
    unsigned u = ((unsigned)h) << 16;
    return __builtin_bit_cast(float, u);
}

// Wpre[sel][tap][o][k] bf16 <- wd[o][k][tap]   (B-operand ready: o rows, k contiguous)
__global__ __launch_bounds__(256) void prep_w(
    const float* __restrict__ wd1, const float* __restrict__ wd2,
    u16* __restrict__ wpre)
{
    int i = blockIdx.x * 256 + threadIdx.x;
    if (i >= 73728) return;
    int sel = i >= 36864;
    int r   = i - sel * 36864;
    int tap = r >> 12;
    int r2  = r & 4095;
    int o   = r2 >> 6, k = r2 & 63;
    const float* ws = sel ? wd2 : wd1;
    wpre[i] = f2bf(ws[o * 576 + k * 9 + tap]);
}

// x NCHW fp32 -> xh NHWC bf16 (pure 64 x HW transpose per n, 64-pixel tiles)
__global__ __launch_bounds__(256) void xpose(
    const float* __restrict__ x, u16* __restrict__ xh)
{
    __shared__ u16 XL[64][66];
    const int tid = threadIdx.x;
    const int n = blockIdx.y;
    const int p0 = blockIdx.x * 64;
    const float* xn = x + (size_t)n * CHW_ + p0;
#pragma unroll
    for (int it = 0; it < 4; ++it) {
        int L = it * 256 + tid;
        int c = L >> 4, g = L & 15;
        float4 v = *(const float4*)(xn + (size_t)c * HW_ + g * 4);
        ushort4 pk = { f2bf(v.x), f2bf(v.y), f2bf(v.z), f2bf(v.w) };
        *(ushort4*)&XL[c][g * 4] = pk;
    }
    __syncthreads();
    u16* dst = xh + (size_t)(n * HW_ + p0) * 64;
#pragma unroll
    for (int it = 0; it < 2; ++it) {
        int L = it * 256 + tid;
        int pix = L >> 3, s = L & 7;
        u16 e0 = XL[s * 8 + 0][pix], e1 = XL[s * 8 + 1][pix];
        u16 e2 = XL[s * 8 + 2][pix], e3 = XL[s * 8 + 3][pix];
        u16 e4 = XL[s * 8 + 4][pix], e5 = XL[s * 8 + 5][pix];
        u16 e6 = XL[s * 8 + 6][pix], e7 = XL[s * 8 + 7][pix];
        uint4 pk = { (unsigned)e0 | ((unsigned)e1 << 16),
                     (unsigned)e2 | ((unsigned)e3 << 16),
                     (unsigned)e4 | ((unsigned)e5 << 16),
                     (unsigned)e6 | ((unsigned)e7 << 16) };
        *(uint4*)(dst + (size_t)pix * 64 + s * 8) = pk;
    }
}

// NHWC 3x3 shared-conv stencil: th = dw(norm(in)) + norm(in); norm = relu(sc*v+sh)
// per channel if ss != null. Lane = channel -> every tap load is 128B coalesced.
__global__ __launch_bounds__(256) void tpass(
    const u16* __restrict__ inh, const float* __restrict__ wsh,
    const float* __restrict__ ss, u16* __restrict__ th)
{
    float wk[9];
#pragma unroll
    for (int k = 0; k < 9; ++k) wk[k] = wsh[k];
    const float wc1 = wk[4] + 1.f;
    const int c = threadIdx.x & 63;
    const bool nrm = (ss != nullptr);
    float sc = 1.f, sh = 0.f;
    if (nrm) { sc = ss[c]; sh = ss[64 + c]; }
    const int stride = gridDim.x * 256;
    const int up = -64 * W_, dn = 64 * W_;
    for (int f = blockIdx.x * 256 + threadIdx.x; f < TOT_; f += stride) {
        int pp = f >> 6;
        int pix = pp % HW_;
        int gh = pix / W_;
        int gw = pix - gh * W_;
        bool ym = gh > 0, yp = gh < H_ - 1, xm = gw > 0, xp = gw < W_ - 1;
        const u16* b = inh + f;
        auto ld = [&](int off, bool ok) -> float {
            if (!ok) return 0.f;
            float r = bf2f(b[off]);
            if (nrm) r = relu_(fmaf(sc, r, sh));
            return r;
        };
        float t = wc1 * ld(0, true);
        t = fmaf(wk[0], ld(up - 64, ym && xm), t);
        t = fmaf(wk[1], ld(up,      ym),       t);
        t = fmaf(wk[2], ld(up + 64, ym && xp), t);
        t = fmaf(wk[3], ld(-64,     xm),       t);
        t = fmaf(wk[5], ld(64,      xp),       t);
        t = fmaf(wk[6], ld(dn - 64, yp && xm), t);
        t = fmaf(wk[7], ld(dn,      yp),       t);
        t = fmaf(wk[8], ld(dn + 64, yp && xp), t);
        th[f] = f2bf(t);
    }
}

// Dense 3x3 conv as implicit GEMM over NHWC bf16 T.
// Tile 32w x 8h; LDS = T-halo [340 pix][64ch] bf16, XOR-swizzled.
// Wave wg owns 16 outputs (o = wg*16 + l15); B frags in registers from Wpre.
// LAYER 1: resid = x fp32 NCHW, dst = o1h bf16 NHWC.
// LAYER 2: resid = relu(bn1(o1h)) from reso+ss, dst = o2 fp32 NCHW.
template<int LAYER>
__global__ __launch_bounds__(256, 3) void conv_mfma(
    const u16* __restrict__ th, const u16* __restrict__ wpre,
    const float* __restrict__ bd, const float* __restrict__ ss,
    const float* __restrict__ resx, const u16* __restrict__ reso,
    u16* __restrict__ dsth, float* __restrict__ dstf,
    float* __restrict__ raw)
{
    __shared__ __align__(16) char TlB[340 * 128];   // 43520 B
    __shared__ float Sr[128];

    const int tid = threadIdx.x;
    const int n = blockIdx.z, h0 = blockIdx.y * 8, w0 = blockIdx.x * 32;
    const int lane = tid & 63, wg = tid >> 6;
    const int l15 = lane & 15, lg = lane >> 4;
    const int o = wg * 16 + l15;

    // B fragments: [tap][cc] -> 18 x bf16x8 in registers (L2-cached source)
    bf8 B[18];
#pragma unroll
    for (int tap = 0; tap < 9; ++tap)
#pragma unroll
        for (int cc = 0; cc < 2; ++cc)
            B[tap * 2 + cc] = *(const bf8*)(wpre + ((tap * 64 + o) * 64 + cc * 32 + lg * 8));

    // Stage T halo (34x10 pixels x 128B), coalesced float4, swizzled LDS
    for (int f = tid; f < 2720; f += 256) {
        int pix = f >> 3, s = f & 7;
        int hr = pix / 34, wc = pix - hr * 34;
        int gh = h0 - 1 + hr, gw = w0 - 1 + wc;
        float4 v = { 0.f, 0.f, 0.f, 0.f };
        if ((unsigned)gh < (unsigned)H_ && (unsigned)gw < (unsigned)W_)
            v = *(const float4*)(th + (size_t)(n * HW_ + gh * W_ + gw) * 64 + s * 8);
        *(float4*)(TlB + pix * 128 + ((s * 16) ^ ((pix & 7) << 4))) = v;
    }
    __syncthreads();

    f4v acc[16];
#pragma unroll
    for (int mf = 0; mf < 16; ++mf) acc[mf] = (f4v){0.f, 0.f, 0.f, 0.f};

#pragma unroll
    for (int mf = 0; mf < 16; ++mf) {
        const int h = mf >> 1, half = mf & 1;
#pragma unroll
        for (int tap = 0; tap < 9; ++tap) {
            const int dr = tap / 3, dc = tap - dr * 3;
            const int hp = (h + dr) * 34 + half * 16 + dc + l15;
#pragma unroll
            for (int cc = 0; cc < 2; ++cc) {
                const bf8 A = *(const bf8*)(TlB + hp * 128 +
                                            ((cc * 64 + lg * 16) ^ ((hp & 7) << 4)));
                acc[mf] = __builtin_amdgcn_mfma_f32_16x16x32_bf16(
                    A, B[tap * 2 + cc], acc[mf], 0, 0, 0);
            }
        }
    }

    // Epilogue: bias + residual + store + per-channel stats
    const float bv = bd[o];
    float scO = 1.f, shO = 0.f;
    if (LAYER == 2) { scO = ss[o]; shO = ss[64 + o]; }
    float ps1 = 0.f, ps2 = 0.f;
#pragma unroll
    for (int mf = 0; mf < 16; ++mf) {
        const int h = h0 + (mf >> 1);
        const int w = w0 + (mf & 1) * 16 + lg * 4;
        const int ppix = n * HW_ + h * W_ + w;
        float vo[4];
        if (LAYER == 1) {
            const float4 rx = *(const float4*)(resx + (size_t)n * CHW_ + (size_t)o * HW_ + h * W_ + w);
            vo[0] = acc[mf][0] + bv + rx.x;
            vo[1] = acc[mf][1] + bv + rx.y;
            vo[2] = acc[mf][2] + bv + rx.z;
            vo[3] = acc[mf][3] + bv + rx.w;
#pragma unroll
            for (int r = 0; r < 4; ++r)
                dsth[(size_t)(ppix + r) * 64 + o] = f2bf(vo[r]);
        } else {
#pragma unroll
            for (int r = 0; r < 4; ++r) {
                float n1 = relu_(fmaf(scO, bf2f(reso[(size_t)(ppix + r) * 64 + o]), shO));
                vo[r] = acc[mf][r] + bv + n1;
            }
            float4 st = { vo[0], vo[1], vo[2], vo[3] };
            *(float4*)(dstf + (size_t)n * CHW_ + (size_t)o * HW_ + h * W_ + w) = st;
        }
        ps1 += (vo[0] + vo[1]) + (vo[2] + vo[3]);
        ps2 += fmaf(vo[0], vo[0], fmaf(vo[1], vo[1], fmaf(vo[2], vo[2], vo[3] * vo[3])));
    }
    ps1 += __shfl_xor(ps1, 16); ps1 += __shfl_xor(ps1, 32);
    ps2 += __shfl_xor(ps2, 16); ps2 += __shfl_xor(ps2, 32);
    if (lane < 16) { Sr[o] = ps1; Sr[64 + o] = ps2; }
    __syncthreads();
    if (tid < 128) atomicAdd(&raw[tid], Sr[tid]);
}

// raw sums -> scale/shift: n = relu(scale*v + shift)
__global__ void stats_fin(const float* __restrict__ raw, const float* __restrict__ gamma,
                          const float* __restrict__ beta, float* __restrict__ ss)
{
    int c = threadIdx.x;
    if (c < 64) {
        const float cnt = (float)(N_ * HW_);
        float mean = raw[c] / cnt;
        float var  = raw[64 + c] / cnt - mean * mean;
        float inv  = rsqrtf(var + 1e-5f);
        float sc   = gamma[c] * inv;
        ss[c]      = sc;
        ss[64 + c] = fmaf(-sc, mean, beta[c]);
    }
}

// io = relu(bn2(io)) + x   (in place on d_out)
__global__ __launch_bounds__(256) void final_k(
    float4* io, const float* __restrict__ ss, const float4* __restrict__ x)
{
    const int nq = TOT_ / 4;
    for (int i = blockIdx.x * 256 + threadIdx.x; i < nq; i += gridDim.x * 256) {
        int c = (i / (HW_ / 4)) & 63;
        float sc = ss[c], sh = ss[64 + c];
        float4 v = io[i], xx = x[i];
        float4 rr;
        rr.x = relu_(fmaf(sc, v.x, sh)) + xx.x;
        rr.y = relu_(fmaf(sc, v.y, sh)) + xx.y;
        rr.z = relu_(fmaf(sc, v.z, sh)) + xx.z;
        rr.w = relu_(fmaf(sc, v.w, sh)) + xx.w;
        io[i] = rr;
    }
}

extern "C" void kernel_launch(void* const* d_in, const int* in_sizes, int n_in,
                              void* d_out, int out_size, void* d_ws, size_t ws_size,
                              hipStream_t stream)
{
    const float* x    = (const float*)d_in[0];
    const float* wsh1 = (const float*)d_in[1];
    const float* wd1  = (const float*)d_in[2];
    const float* bd1  = (const float*)d_in[3];
    const float* wsh2 = (const float*)d_in[4];
    const float* wd2  = (const float*)d_in[5];
    const float* bd2  = (const float*)d_in[6];
    const float* g1   = (const float*)d_in[7];
    const float* be1  = (const float*)d_in[8];
    const float* g2   = (const float*)d_in[9];
    const float* be2  = (const float*)d_in[10];

    float* out = (float*)d_out;
    u16* Th   = (u16*)d_ws;            // TOT_ u16  (T tensor, both layers)
    u16* Xh   = Th + TOT_;             // TOT_ u16  (x NHWC; reused as o1h)
    u16* Wpre = Xh + TOT_;             // 73728 u16
    float* raw1 = (float*)(Wpre + 73728);  // 128
    float* raw2 = raw1 + 128;              // 128
    float* ss1  = raw2 + 128;              // 128
    float* ss2  = ss1 + 128;               // 128

    hipMemsetAsync(raw1, 0, 256 * sizeof(float), stream);
    prep_w<<<288, 256, 0, stream>>>(wd1, wd2, Wpre);

    dim3 xgrid(HW_ / 64, N_);
    dim3 cgrid(W_ / 32, H_ / 8, N_);   // (7, 28, 4)

    // x -> NHWC bf16
    xpose<<<xgrid, 256, 0, stream>>>(x, Xh);
    // T1 = dw(x) + x  (NHWC)
    tpass<<<2048, 256, 0, stream>>>(Xh, wsh1, nullptr, Th);
    // o1 = conv(T1) + b1 + x   -> o1h (bf16 NHWC, overwrites Xh buffer); stats1
    conv_mfma<1><<<cgrid, 256, 0, stream>>>(Th, Wpre, bd1, nullptr, x, nullptr,
                                            Xh, nullptr, raw1);
    stats_fin<<<1, 64, 0, stream>>>(raw1, g1, be1, ss1);
    // T2 = dw(n1) + n1 where n1 = relu(bn1(o1h))  (NHWC)
    tpass<<<2048, 256, 0, stream>>>(Xh, wsh2, ss1, Th);
    // o2 = conv(T2) + b2 + n1 -> d_out (fp32 NCHW); stats2
    conv_mfma<2><<<cgrid, 256, 0, stream>>>(Th, Wpre + 36864, bd2, ss1, nullptr, Xh,
                                            nullptr, out, raw2);
    stats_fin<<<1, 64, 0, stream>>>(raw2, g2, be2, ss2);
    // out = relu(bn2(o2)) + x
    final_k<<<1024, 256, 0, stream>>>((float4*)out, ss2, (const float4*)x);
}